// Round 5
// baseline (876.546 us; speedup 1.0000x reference)
//
#include <hip/hip_runtime.h>
#include <hip/hip_cooperative_groups.h>

namespace cg = cooperative_groups;

typedef unsigned long long u64;
#define THRESH 0.5f
#define ALL1 0xFFFFFFFFFFFFFFFFull
#define FINF __builtin_inff()
#define SCAP 14400
#define MSF   (1 << 29)
#define DONEF (1 << 30)
#define SLOTM ((1 << 29) - 1)

__device__ __forceinline__ u64 shflxU64(u64 v, int m) { return __shfl_xor(v, m, 64); }
// Full bitonic sort of 64 u64 keys (one per lane), ascending across lanes.
__device__ __forceinline__ void sort64(u64 &key, int lane) {
#pragma unroll
    for (int k = 2; k <= 64; k <<= 1) {
#pragma unroll
        for (int j = k >> 1; j > 0; j >>= 1) {
            u64 p = shflxU64(key, j);
            bool takeMax = ((lane & j) != 0) != ((lane & k) != 0);
            u64 mn = key < p ? key : p;
            u64 mx = key < p ? p : key;
            key = takeMax ? mx : mn;
        }
    }
}

// Monotonic (value,id) key: float -> order-preserving u32 (-0 canonicalized to +0
// so float equality == key equality), id in low 32 bits as tiebreak.
__device__ __forceinline__ u64 mkey(float v, int id) {
    v = (v == 0.0f) ? 0.0f : v;
    unsigned u = __float_as_uint(v);
    u ^= (unsigned)((int)u >> 31) | 0x80000000u;
    return ((u64)u << 32) | (unsigned)id;
}

// LDS overlay: count tiles (phases C/F, all blocks) and chain state (phase H,
// block 0 only, strictly after C/F) share the same memory.
union SmemU {
    float f[512];
    u64   k[512];
    int   state[SCAP];
};

__global__ __launch_bounds__(1024, 4) void fused(
    const float* __restrict__ scores, const float* __restrict__ priorities,
    const int* __restrict__ countPtr,
    const float* __restrict__ summaries, const float* __restrict__ pool,
    int N, int P, int D,
    float* __restrict__ outPool, float* __restrict__ outPrior,
    float* __restrict__ outCnt, int* __restrict__ ws)
{
    cg::grid_group gg = cg::this_grid();
    __shared__ SmemU sm;
    __shared__ int shTot, shR, shRp, shLeft;

    const int G = gridDim.x;
    const int b = blockIdx.x;
    const int tid = threadIdx.x;
    const int gtid = b * 1024 + tid;
    const int T = G * 1024;
    const int lane = tid & 63;

    // scratch layout in d_ws (ints)
    int*   srcWs    = ws;                            // P
    float* cval     = (float*)(ws + P);              // N
    int*   csrc     = ws + P + N;                    // N
    float* cvalS    = (float*)(ws + P + 2 * N);      // N
    float* wval     = (float*)(ws + P + 3 * N);      // N
    int*   wsrc     = ws + P + 4 * N;                // N
    int*   writeNum = ws + P + 5 * N;                // N
    float* evV      = (float*)(ws + P + 6 * N);      // N + 64
    int*   evId     = ws + P + 7 * N + 64;           // N + 64
    int*   survW    = ws + P + 8 * N + 128;          // N
    int*   cnt2     = ws + P + 9 * N + 128;          // N
    int*   cnt4     = ws + P + 10 * N + 128;         // P + N
    int*   pcnt     = ws + 2 * P + 11 * N + 128;     // G
    int*   pcnt2    = pcnt + G;                      // G

    int C0 = *countPtr; C0 = C0 < 0 ? 0 : (C0 > P ? P : C0);

    // ---- Phase A: init + per-block valid counts ----
    for (int s = gtid; s < P; s += T) { outPrior[s] = priorities[s]; srcWs[s] = -1; }
    for (int s = gtid; s < N; s += T) cnt2[s] = 0;
    for (int s = gtid; s < P + N; s += T) cnt4[s] = 0;

    const int CHK = (N + G - 1) / G;          // 64 for N=16384, G=256
    const int NSUB = (CHK + 63) >> 6;         // <= 4 supported
    float svr[4];
    if (tid < 64) {
        int c = 0;
#pragma unroll 4
        for (int j = 0; j < 4; ++j) {
            float sc = 0.f;
            if (j < NSUB) {
                const int off = j * 64 + lane;
                const int idx = b * CHK + off;
                if (off < CHK && idx < N) sc = scores[idx];
            }
            svr[j] = sc;
            c += (sc > THRESH) ? 1 : 0;
        }
#pragma unroll
        for (int o = 1; o < 64; o <<= 1) c += __shfl_xor(c, o, 64);
        if (lane == 0) pcnt[b] = c;
    }
    __threadfence();
    gg.sync();   // S1

    // ---- Phase B: block prefix + ordered emit of appends/candidates ----
    if (tid < 64) {
        int s0 = 0, sT = 0;
        for (int j = lane; j < G; j += 64) {
            const int pv = pcnt[j];
            sT += pv;
            if (j < b) s0 += pv;
        }
#pragma unroll
        for (int o = 1; o < 64; o <<= 1) {
            s0 += __shfl_xor(s0, o, 64);
            sT += __shfl_xor(sT, o, 64);
        }
        if (lane == 0) shTot = sT;
        int Aa = P - C0; if (Aa > sT) Aa = sT; if (Aa < 0) Aa = 0;
        int v = s0;
        const u64 laneLt = (1ull << lane) - 1ull;
#pragma unroll 4
        for (int j = 0; j < 4; ++j) {
            if (j < NSUB) {
                const int idx = b * CHK + j * 64 + lane;
                const float sc = svr[j];          // 0 for out-of-range -> invalid
                const bool val = (sc > THRESH);
                const u64 mask = __ballot(val);
                if (val) {
                    const int myv = v + (int)__popcll(mask & laneLt);
                    if (myv < Aa) { outPrior[C0 + myv] = sc; srcWs[C0 + myv] = idx; }
                    else { cval[myv - Aa] = sc; csrc[myv - Aa] = idx; }
                }
                v += (int)__popcll(mask);
            }
        }
    }
    __syncthreads();
    const int total = shTot;
    int A = P - C0; if (A > total) A = total; if (A < 0) A = 0;
    const int F = C0 + A;
    const int M = total - A;
    if (b == 0 && tid == 0) outCnt[0] = (float)F;
    __threadfence();
    gg.sync();   // S2

    // ---- Phase C: k2 dominance counts (success condition) ----
    if (M > 0) {
        const int nEB2 = (M + 1023) >> 10;
        const int TY2 = (F + M + 511) >> 9;
        const int nT2 = nEB2 * TY2;
        for (int task = b; task < nT2; task += G) {
            const int eb = task / TY2;
            const int tt = task - eb * TY2;
            const int iB = eb << 10;
            const int hi = min(M, iB + 1024);
            const int smax = F + hi;
            const int tb = tt << 9;
            if (tb >= smax) continue;             // block-uniform
            const int te = min(smax - tb, 512);
            __syncthreads();
            if (tid < 512) {
                const int s = tb + tid;
                sm.f[tid] = (tid < te) ? ((s < F) ? outPrior[s] : cval[s - F]) : FINF;
            }
            __syncthreads();
            const int i = iB + tid;
            if (i < M) {
                const float x = cval[i];
                int cnt = 0;
                const float4* t4 = (const float4*)sm.f;
                if (tb + 512 <= F + iB) {         // full tile for every element
#pragma unroll 8
                    for (int q = 0; q < 128; ++q) {
                        const float4 w = t4[q];
                        cnt += (w.x < x) + (w.y < x) + (w.z < x) + (w.w < x);
                    }
                } else {
                    int lim = F + i - tb;
                    if (lim < 0) lim = 0;
                    if (lim > te) lim = te;
                    const int l4 = lim >> 2;
                    for (int q = 0; q < l4; ++q) {
                        const float4 w = t4[q];
                        cnt += (w.x < x) + (w.y < x) + (w.z < x) + (w.w < x);
                    }
                    for (int t = l4 << 2; t < lim; ++t) cnt += sm.f[t] < x;
                }
                if (cnt) atomicAdd(&cnt2[i], cnt);
            }
        }
    }
    __threadfence();
    gg.sync();   // S3

    // ---- Phase D: per-block successful-write counts ----
    if (tid < 64) {
        int c = 0;
#pragma unroll 4
        for (int j = 0; j < 4; ++j) {
            if (j < NSUB) {
                const int off = j * 64 + lane;
                const int r = b * CHK + off;
                if (off < CHK && r < M) c += (cnt2[r] >= r + 1) ? 1 : 0;
            }
        }
#pragma unroll
        for (int o = 1; o < 64; o <<= 1) c += __shfl_xor(c, o, 64);
        if (lane == 0) pcnt2[b] = c;
    }
    __threadfence();
    gg.sync();   // S4

    // ---- Phase E: prefix + compact successful writes ----
    if (tid < 64) {
        int s0 = 0, sT = 0;
        for (int j = lane; j < G; j += 64) {
            const int pv = pcnt2[j];
            sT += pv;
            if (j < b) s0 += pv;
        }
#pragma unroll
        for (int o = 1; o < 64; o <<= 1) {
            s0 += __shfl_xor(s0, o, 64);
            sT += __shfl_xor(sT, o, 64);
        }
        if (lane == 0) shR = sT;
        int w = s0;
        const u64 laneLt = (1ull << lane) - 1ull;
#pragma unroll 4
        for (int j = 0; j < 4; ++j) {
            if (j < NSUB) {
                const int off = j * 64 + lane;
                const int r = b * CHK + off;
                const bool in = (off < CHK) && (r < M);
                const bool sc = in && (cnt2[r] >= r + 1);
                const u64 mask = __ballot(sc);
                if (in) {
                    if (sc) {
                        const int myw = w + (int)__popcll(mask & laneLt);
                        wval[myw] = cval[r]; wsrc[myw] = csrc[r];
                        writeNum[r] = myw; cvalS[r] = cval[r];
                    } else { writeNum[r] = -1; cvalS[r] = FINF; }
                }
                w += (int)__popcll(mask);
            }
        }
    }
    __syncthreads();
    const int R = shR;
    __threadfence();
    gg.sync();   // S5

    // ---- Phase F: k4 rank counts via u64 monotonic keys ----
    const int tot = F + M;
    if (M > 0) {
        const int nEB4 = (tot + 1023) >> 10;
        const int TY4 = (tot + 511) >> 9;
        const int nT4 = nEB4 * TY4;
        for (int task = b; task < nT4; task += G) {
            const int eb = task / TY4;
            const int tt = task - eb * TY4;
            const int eB = eb << 10;
            const int tb = tt << 9;
            __syncthreads();
            if (tid < 512) {
                const int s = tb + tid;
                u64 kk = ALL1;
                if (s < tot) {
                    if (s < F) kk = mkey(outPrior[s], s);
                    else       kk = mkey(cvalS[s - F], P + (s - F));
                }
                sm.k[tid] = kk;
            }
            __syncthreads();
            const int e = eB + tid;
            if (e < tot) {
                float x; int id; bool live = true;
                if (e < F) { x = outPrior[e]; id = e; }
                else {
                    x = cvalS[e - F];
                    if (x == FINF) live = false;
                    id = P + (e - F);
                }
                if (live) {
                    const u64 kx = mkey(x, id);
                    int cnt = 0;
                    const ulonglong2* t2 = (const ulonglong2*)sm.k;
#pragma unroll 8
                    for (int q = 0; q < 256; ++q) {
                        const ulonglong2 w2 = t2[q];
                        cnt += (int)(w2.x < kx) + (int)(w2.y < kx);
                    }
                    if (cnt) atomicAdd(&cnt4[e], cnt);
                }
            }
        }
    }
    __threadfence();
    gg.sync();   // S6

    // ---- Phase G: scatter evicted list + survivor flags ----
    if (M > 0) {
        for (int e = gtid; e < tot; e += T) {
            float x; int myid; bool isC = false; int wn = -1;
            if (e < F) { x = outPrior[e]; myid = e; }
            else {
                const int i = e - F;
                x = cvalS[i];
                if (x == FINF) continue;
                isC = true; wn = writeNum[i]; myid = P + i;
            }
            const int cnt = cnt4[e];
            if (isC) survW[wn] = (cnt >= R) ? 1 : 0;
            if (cnt < R + 64) { evV[cnt] = x; evId[cnt] = isC ? (P + wn) : myid; }
        }
    }
    __threadfence();
    gg.sync();   // S7

    // ---- Phase H: block 0 — slot-chain resolution + boundary run + apply ----
    if (b == 0 && R > 0 && R <= SCAP) {
        const int Wtot = F + R;
        if (tid == 0) {
            int Rp = R;
            if (R < Wtot) {
                const float vR1 = evV[R - 1];
                if (evV[R] == vR1) {
                    int rr = R - 1;
                    while (rr >= 0 && evV[rr] == vR1) --rr;
                    Rp = rr + 1;
                }
            }
            shRp = Rp;
        }
        __syncthreads();
        const int Rp = shRp;
        for (int r = tid; r < Rp; r += 1024) sm.state[r] = 0;
        __syncthreads();
        for (int round = 0; round < Rp + 2; ++round) {
            for (int r = tid; r < Rp; r += 1024) {
                if (sm.state[r] & (DONEF | MSF)) continue;
                int cur = r, ms = -1;
                while (true) {
                    const int id = evId[cur];
                    if (id < P) { ms = id; break; }
                    const int p = id - P;
                    if (p >= cur || p < 0) break;
                    const int sp = sm.state[p];
                    if (sp & DONEF) { ms = sp & SLOTM; break; }
                    const float v = evV[p];
                    const bool tiedP = (p > 0 && evV[p - 1] == v) ||
                                       (p + 1 < Rp && evV[p + 1] == v);
                    if (tiedP) break;
                    cur = p;
                }
                if (ms >= 0) {
                    const float v = evV[r];
                    const bool tiedR = (r > 0 && evV[r - 1] == v) ||
                                       (r + 1 < Rp && evV[r + 1] == v);
                    sm.state[r] = ms | (tiedR ? MSF : (MSF | DONEF));
                }
            }
            __syncthreads();
            for (int r = tid; r < Rp; r += 1024) {
                const float v = evV[r];
                if (r > 0 && evV[r - 1] == v) continue;
                if (r + 1 >= Rp || evV[r + 1] != v) continue;
                if (sm.state[r] & DONEF) continue;
                int re = r + 1;
                while (re < Rp && evV[re] == v) ++re;
                bool ready = true;
                for (int s = r; s < re; ++s) ready &= (sm.state[s] & MSF) != 0;
                if (!ready) continue;
                for (int j = r; j < re; ++j) {
                    int best = j;
                    for (int s = j + 1; s < re; ++s)
                        if ((sm.state[s] & SLOTM) < (sm.state[best] & SLOTM)) best = s;
                    const int tmp = sm.state[best];
                    sm.state[best] = sm.state[j];
                    sm.state[j] = tmp;
                }
                for (int j = r; j < re; ++j) sm.state[j] |= DONEF;
            }
            __syncthreads();
            if (tid == 0) shLeft = 0;
            __syncthreads();
            int loc = 0;
            for (int r = tid; r < Rp; r += 1024) loc += (sm.state[r] & DONEF) ? 0 : 1;
            if (loc) atomicAdd(&shLeft, loc);
            __syncthreads();
            if (shLeft == 0) break;
        }
        __syncthreads();
        if (Rp < R && tid < 64) {           // boundary run: e smallest current slots
            const int r = Rp + lane;
            const float v0 = evV[Rp];
            const bool mem = (r < Wtot) && (evV[r] == v0);
            const int g = (int)__popcll(__ballot(mem));
            const int e = R - Rp;
            int id = 0, ms = 0;
            if (mem) {
                id = evId[r];
                ms = (id < P) ? id : (sm.state[id - P] & SLOTM);
            }
            u64 key = mem ? ((((u64)(unsigned)ms) << 32) | (u64)(unsigned)id) : ALL1;
            sort64(key, lane);
            const int sid = (int)(unsigned)(key & 0xFFFFFFFFull);
            const int sms = (int)(unsigned)(key >> 32);
            const bool real = (key != ALL1) && (lane < g);
            if (real && lane < e) sm.state[Rp + lane] = sms;
            if (real && sid >= P) survW[sid - P] = (lane >= e) ? 1 : 0;
        }
        __syncthreads();
        for (int j = tid; j < R; j += 1024) {   // apply surviving writes
            if (survW[j]) {
                const int s = sm.state[j] & SLOTM;
                outPrior[s] = wval[j];
                srcWs[s] = wsrc[j];
            }
        }
    }
    __threadfence();
    gg.sync();   // S8

    // ---- Phase I: gather pool rows ----
    if ((D & 3) == 0) {
        for (int r0 = b * 4 + (tid >> 8); r0 < P; r0 += G * 4) {
            const int s = srcWs[r0];
            const float* row = (s >= 0) ? (summaries + (size_t)s * D)
                                        : (pool + (size_t)r0 * D);
            float* o = outPool + (size_t)r0 * D;
            const int c4 = D >> 2;
            for (int q = (tid & 255); q < c4; q += 256)
                ((float4*)o)[q] = ((const float4*)row)[q];
        }
    } else {
        for (int r0 = b; r0 < P; r0 += G) {
            const int s = srcWs[r0];
            const float* row = (s >= 0) ? (summaries + (size_t)s * D)
                                        : (pool + (size_t)r0 * D);
            float* o = outPool + (size_t)r0 * D;
            for (int k = tid; k < D; k += 1024) o[k] = row[k];
        }
    }
}

extern "C" void kernel_launch(void* const* d_in, const int* in_sizes, int n_in,
                              void* d_out, int out_size, void* d_ws, size_t ws_size,
                              hipStream_t stream) {
    const float* summaries  = (const float*)d_in[0];
    const float* scores     = (const float*)d_in[1];
    const float* pool       = (const float*)d_in[2];
    const float* priorities = (const float*)d_in[3];
    const int*   count      = (const int*)d_in[4];

    int N = in_sizes[1];            // 16384
    int P = in_sizes[3];            // 4096
    int D = in_sizes[0] / N;        // 1024

    float* outPool  = (float*)d_out;
    float* outPrior = outPool + (size_t)P * D;
    float* outCnt   = outPrior + P;
    int*   wsI      = (int*)d_ws;

    // 256 blocks x 1024 threads: all-resident (57.7 KB LDS -> 2 blocks/CU cap),
    // supports N <= 256*256 via <=4 sub-rounds per 64-lane chunk.
    void* args[] = { (void*)&scores, (void*)&priorities, (void*)&count,
                     (void*)&summaries, (void*)&pool,
                     (void*)&N, (void*)&P, (void*)&D,
                     (void*)&outPool, (void*)&outPrior, (void*)&outCnt,
                     (void*)&wsI };
    hipLaunchCooperativeKernel((const void*)fused, dim3(256), dim3(1024),
                               args, 0, stream);
}

// Round 6
// 201.669 us; speedup vs baseline: 4.3465x; 4.3465x over previous
//
#include <hip/hip_runtime.h>

typedef unsigned long long u64;
#define THRESH 0.5f
#define ALL1 0xFFFFFFFFFFFFFFFFull
#define FINF __builtin_inff()
#define SCAP 14400
#define MSF   (1 << 29)
#define DONEF (1 << 30)
#define SLOTM ((1 << 29) - 1)

__device__ __forceinline__ u64 shflxU64(u64 v, int m) { return __shfl_xor(v, m, 64); }
// Full bitonic sort of 64 u64 keys (one per lane), ascending across lanes.
__device__ __forceinline__ void sort64(u64 &key, int lane) {
#pragma unroll
    for (int k = 2; k <= 64; k <<= 1) {
#pragma unroll
        for (int j = k >> 1; j > 0; j >>= 1) {
            u64 p = shflxU64(key, j);
            bool takeMax = ((lane & j) != 0) != ((lane & k) != 0);
            u64 mn = key < p ? key : p;
            u64 mx = key < p ? p : key;
            key = takeMax ? mx : mn;
        }
    }
}

// Monotonic (value,id) key: float -> order-preserving u32 (-0 canonicalized to +0
// so float equality == key equality), id in low 32 bits as tiebreak.
__device__ __forceinline__ u64 mkey(float v, int id) {
    v = (v == 0.0f) ? 0.0f : v;
    unsigned u = __float_as_uint(v);
    u ^= (unsigned)((int)u >> 31) | 0x80000000u;
    return ((u64)u << 32) | (unsigned)id;
}

// ---------------- kA: init, zero counters/tickets, valid scan, appends ----------------
__global__ __launch_bounds__(1024) void kA(
    const float* __restrict__ scores, const float* __restrict__ priorities,
    const int* __restrict__ countPtr, int N, int P,
    float* __restrict__ outPrior, float* __restrict__ outCnt, int* __restrict__ srcWs,
    float* __restrict__ cval, int* __restrict__ csrc, int* __restrict__ meta,
    int* __restrict__ cnt2, int* __restrict__ cnt4, int* __restrict__ tickets)
{
    const int tid = threadIdx.x;
    for (int s = tid; s < P; s += 1024) { outPrior[s] = priorities[s]; srcWs[s] = -1; }
    for (int s = tid; s < N; s += 1024) cnt2[s] = 0;
    for (int s = tid; s < P + N; s += 1024) cnt4[s] = 0;
    if (tid == 0) { tickets[0] = 0; tickets[1] = 0; }
    int C0 = *countPtr; C0 = C0 < 0 ? 0 : (C0 > P ? P : C0);
    const int per = (N + 1023) >> 10;
    const int i0 = tid * per;
    float sv[16];
    if (per == 16 && i0 + 16 <= N) {
        const float4* s4 = (const float4*)(scores + i0);
        const float4 a = s4[0], b = s4[1], c4 = s4[2], d = s4[3];
        sv[0]=a.x; sv[1]=a.y; sv[2]=a.z; sv[3]=a.w;
        sv[4]=b.x; sv[5]=b.y; sv[6]=b.z; sv[7]=b.w;
        sv[8]=c4.x; sv[9]=c4.y; sv[10]=c4.z; sv[11]=c4.w;
        sv[12]=d.x; sv[13]=d.y; sv[14]=d.z; sv[15]=d.w;
    } else {
#pragma unroll 16
        for (int j = 0; j < 16; ++j)
            sv[j] = (j < per && i0 + j < N) ? scores[i0 + j] : 0.f;
    }
    int c = 0;
#pragma unroll 16
    for (int j = 0; j < 16; ++j) c += (j < per && i0 + j < N && sv[j] > THRESH) ? 1 : 0;
    __shared__ int sb[1024];
    sb[tid] = c; __syncthreads();
    for (int off = 1; off < 1024; off <<= 1) {
        int v = (tid >= off) ? sb[tid - off] : 0;
        __syncthreads();
        sb[tid] += v;
        __syncthreads();
    }
    const int total = sb[1023];
    int v = sb[tid] - c;  // exclusive prefix of valid count
    int A = P - C0; if (A > total) A = total; if (A < 0) A = 0;
#pragma unroll 16
    for (int j = 0; j < 16; ++j) {
        if (j < per && i0 + j < N) {
            const float sc = sv[j];
            if (sc > THRESH) {
                if (v < A) { outPrior[C0 + v] = sc; srcWs[C0 + v] = i0 + j; }
                else { cval[v - A] = sc; csrc[v - A] = i0 + j; }
                ++v;
            }
        }
    }
    if (tid == 0) {
        meta[0] = total - A;      // M: number of replacement candidates
        meta[1] = C0 + A;         // F: filled pool size after appends
        outCnt[0] = (float)(C0 + A);
    }
}

// ---------------- kB: k2 dominance count grid + last-block k3 compaction ----------------
// cnt2[i] = #{V < c_i} + #{j<i : c_j < c_i}; cand i succeeds iff cnt2[i] >= i+1.
// Last block (ticket) compacts successful writes. Cross-block data flows only via
// device atomics; __syncthreads drains vmcnt before the ticket increment.
__global__ __launch_bounds__(1024) void kB(
    const float* __restrict__ outPrior, const float* __restrict__ cval,
    const int* __restrict__ csrc, int* __restrict__ meta,
    int* __restrict__ cnt2, int* __restrict__ tickets,
    float* __restrict__ cvalS, float* __restrict__ wval, int* __restrict__ wsrc,
    int* __restrict__ writeNum)
{
    __shared__ __align__(16) union { float tile[512]; int sb[1024]; } sm;
    __shared__ int shLast;
    const int tid = threadIdx.x;
    const int M = meta[0], F = meta[1];

    // counting phase (block-uniform live test)
    const int iB = (int)blockIdx.x << 10;
    const int tb = (int)blockIdx.y << 9;
    int te = 0;
    if (iB < M) {
        const int hi = min(M, iB + 1024);
        const int smax = F + hi;
        if (tb < smax) te = min(smax - tb, 512);
    }
    if (te > 0) {
        if (tid < 512) {
            const int s = tb + tid;
            sm.tile[tid] = (tid < te) ? ((s < F) ? outPrior[s] : cval[s - F]) : FINF;
        }
        __syncthreads();
        const int i = iB + tid;
        if (i < M) {
            const float x = cval[i];
            int cnt = 0;
            const float4* t4 = (const float4*)sm.tile;
            if (tb + 512 <= F + iB) {             // full tile for every elem in block
#pragma unroll 8
                for (int q = 0; q < 128; ++q) {
                    const float4 w = t4[q];
                    cnt += (w.x < x) + (w.y < x) + (w.z < x) + (w.w < x);
                }
            } else {
                int lim = F + i - tb;
                if (lim < 0) lim = 0;
                if (lim > te) lim = te;
                const int l4 = lim >> 2;
                for (int q = 0; q < l4; ++q) {
                    const float4 w = t4[q];
                    cnt += (w.x < x) + (w.y < x) + (w.z < x) + (w.w < x);
                }
                for (int t = l4 << 2; t < lim; ++t) cnt += sm.tile[t] < x;
            }
            if (cnt) atomicAdd(&cnt2[i], cnt);
        }
    }
    __syncthreads();   // drains vmcnt(0): this block's cnt2 atomics are performed
    if (tid == 0)
        shLast = (atomicAdd(&tickets[0], 1) == (int)(gridDim.x * gridDim.y) - 1);
    __syncthreads();
    if (!shLast) return;

    // ---- last block: k3 compaction (identical order semantics to round 4) ----
    const int per = (M + 1023) >> 10;
    const int i0 = tid * per, i1 = min(i0 + per, M);
    int cv[16];
    int c = 0;
    for (int i = i0, j = 0; i < i1; ++i, ++j) {
        const int q = atomicAdd(&cnt2[i], 0);     // coherence-point read
        cv[j] = q;
        c += (q >= i + 1) ? 1 : 0;
    }
    __syncthreads();                              // before reusing sm as sb
    sm.sb[tid] = c; __syncthreads();
    for (int off = 1; off < 1024; off <<= 1) {
        int v = (tid >= off) ? sm.sb[tid - off] : 0;
        __syncthreads();
        sm.sb[tid] += v;
        __syncthreads();
    }
    int w = sm.sb[tid] - c;
    for (int i = i0, j = 0; i < i1; ++i, ++j) {
        if (cv[j] >= i + 1) {
            wval[w] = cval[i]; wsrc[w] = csrc[i]; writeNum[i] = w; cvalS[i] = cval[i]; ++w;
        } else { writeNum[i] = -1; cvalS[i] = FINF; }
    }
    if (tid == 0) meta[2] = sm.sb[1023];          // R: number of successful writes
}

// ---------------- kC: k4 rank count grid + last-block scatter/chain/apply ----------------
__global__ __launch_bounds__(1024) void kC(
    float* __restrict__ outPrior, const float* __restrict__ cvalS,
    const int* __restrict__ writeNum, const int* __restrict__ meta, int P,
    int* __restrict__ cnt4, int* __restrict__ tickets,
    float* __restrict__ evV, int* __restrict__ evId, int* __restrict__ survW,
    const float* __restrict__ wval, const int* __restrict__ wsrc,
    int* __restrict__ srcWs)
{
    __shared__ __align__(16) union { u64 tile[512]; int state[SCAP]; } sm;
    __shared__ int shLast, shRp, shLeft;
    const int tid = threadIdx.x;
    const int M = meta[0], F = meta[1];
    const int tot = F + M;

    // counting phase: 2 elems/thread (eB+tid, eB+1024+tid), u64 monotonic keys
    const int eB = (int)blockIdx.x << 11;
    const int tb = (int)blockIdx.y << 9;
    int te = 0;
    if (M > 0 && eB < tot && tb < tot) te = min(tot - tb, 512);
    if (te > 0) {
        if (tid < 512) {
            const int s = tb + tid;
            u64 kk = ALL1;
            if (tid < te) {
                if (s < F) kk = mkey(outPrior[s], s);
                else       kk = mkey(cvalS[s - F], P + (s - F));
            }
            sm.tile[tid] = kk;
        }
        __syncthreads();
        const ulonglong2* t2 = (const ulonglong2*)sm.tile;
#pragma unroll 2
        for (int h = 0; h < 2; ++h) {
            const int e = eB + (h << 10) + tid;
            if (e < tot) {
                float x; int id; bool live = true;
                if (e < F) { x = outPrior[e]; id = e; }
                else {
                    x = cvalS[e - F];
                    if (x == FINF) live = false;
                    id = P + (e - F);
                }
                if (live) {
                    const u64 kx = mkey(x, id);
                    int cnt = 0;
#pragma unroll 8
                    for (int q = 0; q < 256; ++q) {
                        const ulonglong2 w2 = t2[q];
                        cnt += (int)(w2.x < kx) + (int)(w2.y < kx);
                    }
                    if (cnt) atomicAdd(&cnt4[e], cnt);
                }
            }
        }
    }
    __syncthreads();   // drains vmcnt(0): this block's cnt4 atomics are performed
    if (tid == 0)
        shLast = (atomicAdd(&tickets[1], 1) == (int)(gridDim.x * gridDim.y) - 1);
    __syncthreads();
    if (!shLast) return;

    // ---- last block: scatter evicted list + survivor flags ----
    const int R = meta[2];
    if (M > 0) {
        for (int e = tid; e < tot; e += 1024) {
            float x; int myid; bool isC = false; int wn = -1;
            if (e < F) { x = outPrior[e]; myid = e; }
            else {
                const int i = e - F;
                x = cvalS[i];
                if (x == FINF) continue;
                isC = true; wn = writeNum[i]; myid = P + i;
            }
            const int cnt = atomicAdd(&cnt4[e], 0);   // coherence-point read
            if (isC) survW[wn] = (cnt >= R) ? 1 : 0;
            if (cnt < R + 64) { evV[cnt] = x; evId[cnt] = isC ? (P + wn) : myid; }
        }
    }
    __syncthreads();   // evV/evId/survW visible block-wide

    if (R <= 0 || R > SCAP) return;
    const int Wtot = F + R;

    // Rp: start of the equal-value run straddling the evicted/survivor boundary
    if (tid == 0) {
        int Rp = R;
        if (R < Wtot) {
            const float vR1 = evV[R - 1];
            if (evV[R] == vR1) {
                int rr = R - 1;
                while (rr >= 0 && evV[rr] == vR1) --rr;
                Rp = rr + 1;
            }
        }
        shRp = Rp;
    }
    __syncthreads();
    const int Rp = shRp;

    for (int r = tid; r < Rp; r += 1024) sm.state[r] = 0;
    __syncthreads();

    for (int round = 0; round < Rp + 2; ++round) {
        for (int r = tid; r < Rp; r += 1024) {
            if (sm.state[r] & (DONEF | MSF)) continue;
            int cur = r, ms = -1;
            while (true) {
                const int id = evId[cur];
                if (id < P) { ms = id; break; }
                const int p = id - P;
                if (p >= cur || p < 0) break;
                const int sp = sm.state[p];
                if (sp & DONEF) { ms = sp & SLOTM; break; }
                const float v = evV[p];
                const bool tiedP = (p > 0 && evV[p - 1] == v) ||
                                   (p + 1 < Rp && evV[p + 1] == v);
                if (tiedP) break;
                cur = p;
            }
            if (ms >= 0) {
                const float v = evV[r];
                const bool tiedR = (r > 0 && evV[r - 1] == v) ||
                                   (r + 1 < Rp && evV[r + 1] == v);
                sm.state[r] = ms | (tiedR ? MSF : (MSF | DONEF));
            }
        }
        __syncthreads();
        for (int r = tid; r < Rp; r += 1024) {
            const float v = evV[r];
            if (r > 0 && evV[r - 1] == v) continue;
            if (r + 1 >= Rp || evV[r + 1] != v) continue;
            if (sm.state[r] & DONEF) continue;
            int re = r + 1;
            while (re < Rp && evV[re] == v) ++re;
            bool ready = true;
            for (int s = r; s < re; ++s) ready &= (sm.state[s] & MSF) != 0;
            if (!ready) continue;
            for (int j = r; j < re; ++j) {
                int best = j;
                for (int s = j + 1; s < re; ++s)
                    if ((sm.state[s] & SLOTM) < (sm.state[best] & SLOTM)) best = s;
                const int tmp = sm.state[best];
                sm.state[best] = sm.state[j];
                sm.state[j] = tmp;
            }
            for (int j = r; j < re; ++j) sm.state[j] |= DONEF;
        }
        __syncthreads();
        if (tid == 0) shLeft = 0;
        __syncthreads();
        int loc = 0;
        for (int r = tid; r < Rp; r += 1024) loc += (sm.state[r] & DONEF) ? 0 : 1;
        if (loc) atomicAdd(&shLeft, loc);
        __syncthreads();
        if (shLeft == 0) break;
    }
    __syncthreads();

    if (Rp < R && tid < 64) {        // boundary run: e smallest current slots
        const int lane = tid;
        const int r = Rp + lane;
        const float v0 = evV[Rp];
        const bool mem = (r < Wtot) && (evV[r] == v0);
        const int g = (int)__popcll(__ballot(mem));
        const int e = R - Rp;
        int id = 0, ms = 0;
        if (mem) {
            id = evId[r];
            ms = (id < P) ? id : (sm.state[id - P] & SLOTM);
        }
        u64 key = mem ? ((((u64)(unsigned)ms) << 32) | (u64)(unsigned)id) : ALL1;
        sort64(key, lane);
        const int sid = (int)(unsigned)(key & 0xFFFFFFFFull);
        const int sms = (int)(unsigned)(key >> 32);
        const bool real = (key != ALL1) && (lane < g);
        if (real && lane < e) sm.state[Rp + lane] = sms;
        if (real && sid >= P) survW[sid - P] = (lane >= e) ? 1 : 0;
    }
    __syncthreads();

    for (int j = tid; j < R; j += 1024) {   // apply surviving writes
        if (survW[j]) {
            const int s = sm.state[j] & SLOTM;
            outPrior[s] = wval[j];
            srcWs[s] = wsrc[j];
        }
    }
}

// ---------------- kD: gather, one block per pool row ----------------
__global__ __launch_bounds__(256) void gather_kernel(
    const float* __restrict__ summaries,
    const float* __restrict__ pool,
    const int* __restrict__ src,
    float* __restrict__ outPool, int D) {
    int p = blockIdx.x;
    int s = src[p];
    const float* row = (s >= 0) ? (summaries + (size_t)s * D) : (pool + (size_t)p * D);
    float* o = outPool + (size_t)p * D;
    if ((D & 3) == 0) {
        for (int k = (threadIdx.x << 2); k < D; k += (blockDim.x << 2)) {
            float4 v = *(const float4*)(row + k);
            *(float4*)(o + k) = v;
        }
    } else {
        for (int k = threadIdx.x; k < D; k += blockDim.x) o[k] = row[k];
    }
}

extern "C" void kernel_launch(void* const* d_in, const int* in_sizes, int n_in,
                              void* d_out, int out_size, void* d_ws, size_t ws_size,
                              hipStream_t stream) {
    const float* summaries  = (const float*)d_in[0];
    const float* scores     = (const float*)d_in[1];
    const float* pool       = (const float*)d_in[2];
    const float* priorities = (const float*)d_in[3];
    const int*   count      = (const int*)d_in[4];

    int N = in_sizes[1];            // 16384
    int P = in_sizes[3];            // 4096
    int D = in_sizes[0] / N;        // 1024

    float* outPool  = (float*)d_out;
    float* outPrior = outPool + (size_t)P * D;
    float* outCnt   = outPrior + P;

    // all scratch in d_ws
    int*   ws       = (int*)d_ws;
    int*   srcWs    = ws;                            // P
    float* cval     = (float*)(ws + P);              // N
    int*   csrc     = ws + P + N;                    // N
    float* cvalS    = (float*)(ws + P + 2 * N);      // N
    float* wval     = (float*)(ws + P + 3 * N);      // N
    int*   wsrc     = ws + P + 4 * N;                // N
    int*   writeNum = ws + P + 5 * N;                // N
    float* evV      = (float*)(ws + P + 6 * N);      // N + 64
    int*   evId     = ws + P + 7 * N + 64;           // N + 64
    int*   survW    = ws + P + 8 * N + 128;          // N
    int*   cnt2     = ws + P + 9 * N + 128;          // N
    int*   cnt4     = ws + P + 10 * N + 128;         // P + N
    int*   meta     = ws + 2 * P + 11 * N + 128;     // 8
    int*   tickets  = meta + 8;                      // 2

    const dim3 gB((N + 1023) / 1024, (P + N + 511) / 512);        // worst-case M=N
    const dim3 gC((P + N + 2047) / 2048, (P + N + 511) / 512);    // worst-case tot=P+N

    kA<<<1, 1024, 0, stream>>>(scores, priorities, count, N, P,
                               outPrior, outCnt, srcWs, cval, csrc, meta,
                               cnt2, cnt4, tickets);
    kB<<<gB, 1024, 0, stream>>>(outPrior, cval, csrc, meta, cnt2, tickets,
                                cvalS, wval, wsrc, writeNum);
    kC<<<gC, 1024, 0, stream>>>(outPrior, cvalS, writeNum, meta, P, cnt4, tickets,
                                evV, evId, survW, wval, wsrc, srcWs);
    gather_kernel<<<P, 256, 0, stream>>>(summaries, pool, srcWs, outPool, D);
}

// Round 7
// 181.011 us; speedup vs baseline: 4.8425x; 1.1141x over previous
//
#include <hip/hip_runtime.h>

typedef unsigned long long u64;
#define THRESH 0.5f
#define ALL1 0xFFFFFFFFFFFFFFFFull
#define FINF __builtin_inff()

__device__ __forceinline__ u64 shflxU64(u64 v, int m) { return __shfl_xor(v, m, 64); }
// Full bitonic sort of 64 u64 keys (one per lane), ascending across lanes.
__device__ __forceinline__ void sort64(u64 &key, int lane) {
#pragma unroll
    for (int k = 2; k <= 64; k <<= 1) {
#pragma unroll
        for (int j = k >> 1; j > 0; j >>= 1) {
            u64 p = shflxU64(key, j);
            bool takeMax = ((lane & j) != 0) != ((lane & k) != 0);
            u64 mn = key < p ? key : p;
            u64 mx = key < p ? p : key;
            key = takeMax ? mx : mn;
        }
    }
}

// Monotonic (value,id) key: float -> order-preserving u32 (-0 canonicalized to +0
// so float equality == key equality), id in low 32 bits as tiebreak.
__device__ __forceinline__ u64 mkey(float v, int id) {
    v = (v == 0.0f) ? 0.0f : v;
    unsigned u = __float_as_uint(v);
    u ^= (unsigned)((int)u >> 31) | 0x80000000u;
    return ((u64)u << 32) | (unsigned)id;
}

// ---------------- K1: valid scan, appends, candidate compaction ----------------
__global__ __launch_bounds__(1024) void k1_scan(
    const float* __restrict__ scores, const float* __restrict__ priorities,
    const int* __restrict__ countPtr, int N, int P,
    float* __restrict__ outPrior, float* __restrict__ outCnt, int* __restrict__ srcWs,
    float* __restrict__ cval, int* __restrict__ csrc, int* __restrict__ meta)
{
    const int tid = threadIdx.x;
    for (int s = tid; s < P; s += 1024) { outPrior[s] = priorities[s]; srcWs[s] = -1; }
    int C0 = *countPtr; C0 = C0 < 0 ? 0 : (C0 > P ? P : C0);
    const int per = (N + 1023) >> 10;
    const int i0 = tid * per;
    float sv[16];
    if (per == 16 && i0 + 16 <= N) {
        const float4* s4 = (const float4*)(scores + i0);
        const float4 a = s4[0], b = s4[1], c4 = s4[2], d = s4[3];
        sv[0]=a.x; sv[1]=a.y; sv[2]=a.z; sv[3]=a.w;
        sv[4]=b.x; sv[5]=b.y; sv[6]=b.z; sv[7]=b.w;
        sv[8]=c4.x; sv[9]=c4.y; sv[10]=c4.z; sv[11]=c4.w;
        sv[12]=d.x; sv[13]=d.y; sv[14]=d.z; sv[15]=d.w;
    } else {
#pragma unroll 16
        for (int j = 0; j < 16; ++j)
            sv[j] = (j < per && i0 + j < N) ? scores[i0 + j] : 0.f;
    }
    int c = 0;
#pragma unroll 16
    for (int j = 0; j < 16; ++j) c += (j < per && i0 + j < N && sv[j] > THRESH) ? 1 : 0;
    __shared__ int sb[1024];
    sb[tid] = c; __syncthreads();
    for (int off = 1; off < 1024; off <<= 1) {
        int v = (tid >= off) ? sb[tid - off] : 0;
        __syncthreads();
        sb[tid] += v;
        __syncthreads();
    }
    const int total = sb[1023];
    int v = sb[tid] - c;  // exclusive prefix of valid count
    int A = P - C0; if (A > total) A = total; if (A < 0) A = 0;
#pragma unroll 16
    for (int j = 0; j < 16; ++j) {
        if (j < per && i0 + j < N) {
            const float sc = sv[j];
            if (sc > THRESH) {
                if (v < A) { outPrior[C0 + v] = sc; srcWs[C0 + v] = i0 + j; }
                else { cval[v - A] = sc; csrc[v - A] = i0 + j; }
                ++v;
            }
        }
    }
    if (tid == 0) {
        meta[0] = total - A;      // M: number of replacement candidates
        meta[1] = C0 + A;         // F: filled pool size after appends
        outCnt[0] = (float)(C0 + A);
    }
}

// ---------------- K2: split dominance count for success condition ----------------
// cnt2[i] = #{V < c_i} + #{j<i : c_j < c_i}; cand i succeeds iff cnt2[i] >= i+1.
#define K2T 512
__global__ __launch_bounds__(256) void k2_count(
    const float* __restrict__ outPrior, const float* __restrict__ cval,
    const int* __restrict__ meta, int* __restrict__ cnt2)
{
    const int M = meta[0], F = meta[1];
    const int iB = blockIdx.x << 8;
    if (iB >= M) return;
    const int hi = min(M, iB + 256);
    const int smax = F + hi;              // exclusive max source index this block needs
    const int tb = blockIdx.y * K2T;
    if (tb >= smax) return;
    const int te = min(smax - tb, K2T);
    __shared__ __align__(16) float tile[K2T];
    for (int t = threadIdx.x; t < K2T; t += 256) {
        const int s = tb + t;
        tile[t] = (t < te) ? ((s < F) ? outPrior[s] : cval[s - F]) : FINF;
    }
    __syncthreads();
    const int i = iB + threadIdx.x;
    if (i >= M) return;
    const float x = cval[i];
    int cnt = 0;
    const float4* t4 = (const float4*)tile;
    if (tb + K2T <= F + iB) {             // full tile for every thread in block
#pragma unroll 8
        for (int q = 0; q < K2T / 4; ++q) {
            const float4 w = t4[q];
            cnt += (w.x < x) + (w.y < x) + (w.z < x) + (w.w < x);
        }
    } else {
        int lim = F + i - tb;
        if (lim < 0) lim = 0;
        if (lim > te) lim = te;
        const int l4 = lim >> 2;
        for (int q = 0; q < l4; ++q) {
            const float4 w = t4[q];
            cnt += (w.x < x) + (w.y < x) + (w.z < x) + (w.w < x);
        }
        for (int t = l4 << 2; t < lim; ++t) cnt += tile[t] < x;
    }
    if (cnt) atomicAdd(&cnt2[i], cnt);
}

// ---------------- K3: succ from cnt2, scan -> write numbers, compact writes ----------------
__global__ __launch_bounds__(1024) void k3_compact(
    const float* __restrict__ cval, const int* __restrict__ csrc,
    const int* __restrict__ cnt2, int* __restrict__ meta,
    float* __restrict__ cvalS, float* __restrict__ wval, int* __restrict__ wsrc,
    int* __restrict__ writeNum)
{
    const int M = meta[0];
    const int tid = threadIdx.x;
    const int per = (M + 1023) >> 10;
    const int i0 = tid * per, i1 = min(i0 + per, M);
    int c = 0;
    for (int i = i0; i < i1; ++i) c += (cnt2[i] >= i + 1) ? 1 : 0;
    __shared__ int sb[1024];
    sb[tid] = c; __syncthreads();
    for (int off = 1; off < 1024; off <<= 1) {
        int v = (tid >= off) ? sb[tid - off] : 0;
        __syncthreads();
        sb[tid] += v;
        __syncthreads();
    }
    int w = sb[tid] - c;
    for (int i = i0; i < i1; ++i) {
        if (cnt2[i] >= i + 1) {
            wval[w] = cval[i]; wsrc[w] = csrc[i]; writeNum[i] = w; cvalS[i] = cval[i]; ++w;
        } else { writeNum[i] = -1; cvalS[i] = FINF; }
    }
    if (tid == 0) meta[2] = sb[1023];   // R: number of successful writes
}

// ---------------- K4a: rank count in W = V ∪ C_succ via u64 monotonic keys ----------------
#define K4T 512
__global__ __launch_bounds__(256) void k4_count(
    const float* __restrict__ outPrior, const float* __restrict__ cvalS,
    const int* __restrict__ meta, int P, int* __restrict__ cnt4)
{
    const int M = meta[0], F = meta[1];
    if (M == 0) return;
    const int tot = F + M;
    const int eB = blockIdx.x << 8;
    if (eB >= tot) return;
    const int tb = blockIdx.y * K4T;
    if (tb >= tot) return;
    const int te = min(tot - tb, K4T);
    __shared__ __align__(16) u64 tile[K4T];
    for (int t = threadIdx.x; t < K4T; t += 256) {
        const int s = tb + t;
        u64 kk = ALL1;
        if (t < te) {
            if (s < F) kk = mkey(outPrior[s], s);
            else       kk = mkey(cvalS[s - F], P + (s - F));
        }
        tile[t] = kk;
    }
    __syncthreads();
    const int e = eB + threadIdx.x;
    if (e >= tot) return;
    float x; int id;
    if (e < F) { x = outPrior[e]; id = e; }
    else {
        x = cvalS[e - F];
        if (x == FINF) return;
        id = P + (e - F);
    }
    const u64 kx = mkey(x, id);
    int cnt = 0;
    const ulonglong2* t2 = (const ulonglong2*)tile;
#pragma unroll 8
    for (int q = 0; q < K4T / 2; ++q) {
        const ulonglong2 w = t2[q];
        cnt += (int)(w.x < kx) + (int)(w.y < kx);
    }
    if (cnt) atomicAdd(&cnt4[e], cnt);
}

// ---------------- K4b: scatter evicted list + survivor flags from final ranks ----------------
__global__ __launch_bounds__(256) void k4_scatter(
    const float* __restrict__ outPrior, const float* __restrict__ cvalS,
    const int* __restrict__ writeNum, const int* __restrict__ meta, int P,
    const int* __restrict__ cnt4,
    float* __restrict__ evV, int* __restrict__ evId, int* __restrict__ survW)
{
    const int M = meta[0], F = meta[1], R = meta[2];
    if (M == 0) return;
    const int tot = F + M;
    const int e = blockIdx.x * 256 + threadIdx.x;
    if (e >= tot) return;
    float x; int myid; bool isCand = false; int wn = -1;
    if (e < F) { x = outPrior[e]; myid = e; }
    else {
        const int i = e - F;
        x = cvalS[i];
        if (x == FINF) return;
        isCand = true; wn = writeNum[i]; myid = P + i;
    }
    const int cnt = cnt4[e];
    if (isCand) survW[wn] = (cnt >= R) ? 1 : 0;
    if (cnt < R + 64) { evV[cnt] = x; evId[cnt] = isCand ? (P + wn) : myid; }
}

// ---------------- K5: LDS-resident slot-chain resolution + apply ----------------
// state[r] encoding: payload (27b) = parent rank (unresolved) or slot (resolved);
// MSF = slot known; DONEF = final (walkers may consume); TIEF = member of an
// equal-value run; RSF = run start. Semantics identical to prior rounds: chains
// through untied ranks pass slots down; tied runs assign members (sorted by
// current slot ascending) in rank order; boundary run straddling R gives its e
// lowest current slots to the e evictions.
#define SCAP 14400
#define DONEF (1 << 30)
#define MSF   (1 << 29)
#define TIEF  (1 << 28)
#define RSF   (1 << 27)
#define PAYM  ((1 << 27) - 1)
__global__ __launch_bounds__(1024) void k5_chain(
    const float* __restrict__ evV, const int* __restrict__ evId,
    const int* __restrict__ meta, int P,
    const float* __restrict__ wval, const int* __restrict__ wsrc,
    int* __restrict__ survW,
    float* __restrict__ outPrior, int* __restrict__ srcWs)
{
    __shared__ int state[SCAP];
    __shared__ int shRp, shLeft;
    const int tid = threadIdx.x;
    const int R = meta[2];
    if (R <= 0 || R > SCAP) return;
    const int F = meta[1];
    const int Wtot = F + R;

    // Rp: start of the equal-value run straddling the evicted/survivor boundary
    if (tid == 0) {
        int Rp = R;
        if (R < Wtot) {
            const float vR1 = evV[R - 1];
            if (evV[R] == vR1) {
                int rr = R - 1;
                while (rr >= 0 && evV[rr] == vR1) --rr;
                Rp = rr + 1;
            }
        }
        shRp = Rp;
    }
    __syncthreads();
    const int Rp = shRp;

    // init: one coalesced global pass; all later rounds are pure LDS
    for (int r = tid; r < Rp; r += 1024) {
        const float v = evV[r];
        const bool tp = (r > 0) && (evV[r - 1] == v);
        const bool tn = (r + 1 < Rp) && (evV[r + 1] == v);
        const bool tie = tp || tn;
        const int rs = (tie && !tp) ? RSF : 0;
        const int id = evId[r];
        int st;
        if (id < P) st = id | MSF | (tie ? (TIEF | rs) : DONEF);   // root
        else        st = (id - P) | (tie ? (TIEF | rs) : 0);       // parent-encoding
        state[r] = st;
    }
    __syncthreads();

    for (int round = 0; round < Rp + 2; ++round) {
        // walk phase: follow parents in LDS until DONE ancestor or pending tie
        for (int r = tid; r < Rp; r += 1024) {
            const int s = state[r];
            if (s & MSF) continue;
            int p = s & PAYM;
            int ms = -1;
            for (int g = 0; g < Rp + 2; ++g) {
                const int sp = state[p];
                if (sp & DONEF) { ms = sp & PAYM; break; }
                if (sp & (MSF | TIEF)) break;       // blocked: tie pending sort
                const int q = sp & PAYM;
                if (q >= p) break;                  // malformed guard
                p = q;
            }
            if (ms >= 0)
                state[r] = ms | MSF | ((s & TIEF) ? (s & (TIEF | RSF)) : DONEF);
            else
                state[r] = p | (s & (TIEF | RSF));  // path compression
        }
        __syncthreads();
        // run-sort phase: leader = run start; sort member slots ascending
        for (int r = tid; r < Rp; r += 1024) {
            const int s = state[r];
            if (!(s & RSF) || (s & DONEF)) continue;
            int re = r + 1;
            while (re < Rp) {
                const int t = state[re];
                if ((t & TIEF) && !(t & RSF)) ++re; else break;
            }
            bool ready = true;
            for (int q = r; q < re; ++q) ready &= (state[q] & MSF) != 0;
            if (!ready) continue;
            for (int j = r; j < re; ++j) {          // selection sort on payloads
                int best = j;
                for (int q = j + 1; q < re; ++q)
                    if ((state[q] & PAYM) < (state[best] & PAYM)) best = q;
                if (best != j) {
                    const int pj = state[j] & PAYM, pb = state[best] & PAYM;
                    state[j]    = (state[j] & ~PAYM) | pb;
                    state[best] = (state[best] & ~PAYM) | pj;
                }
            }
            for (int j = r; j < re; ++j) state[j] |= DONEF;
        }
        __syncthreads();
        if (tid == 0) shLeft = 0;
        __syncthreads();
        int loc = 0;
        for (int r = tid; r < Rp; r += 1024) loc += (state[r] & DONEF) ? 0 : 1;
        if (loc) atomicAdd(&shLeft, loc);
        __syncthreads();
        if (shLeft == 0) break;
    }
    __syncthreads();

    // boundary run [Rp, R): e evictions take the e smallest current slots
    if (Rp < R && tid < 64) {
        const int lane = tid;
        const int r = Rp + lane;
        const float v0 = evV[Rp];
        const bool mem = (r < Wtot) && (evV[r] == v0);
        const int g = (int)__popcll(__ballot(mem));
        const int e = R - Rp;
        int id = 0, ms = 0;
        if (mem) {
            id = evId[r];
            ms = (id < P) ? id : (state[id - P] & PAYM);
        }
        u64 key = mem ? ((((u64)(unsigned)ms) << 32) | (u64)(unsigned)id) : ALL1;
        sort64(key, lane);
        const int sid = (int)(unsigned)(key & 0xFFFFFFFFull);
        const int sms = (int)(unsigned)(key >> 32);
        const bool real = (key != ALL1) && (lane < g);
        if (real && lane < e) state[Rp + lane] = sms;   // payload-only (flags 0)
        if (real && sid >= P) survW[sid - P] = (lane >= e) ? 1 : 0;
    }
    __syncthreads();

    // apply surviving writes
    for (int j = tid; j < R; j += 1024) {
        if (survW[j]) {
            const int sl = state[j] & PAYM;
            outPrior[sl] = wval[j];
            srcWs[sl] = wsrc[j];
        }
    }
}

// ---------------- gather: one block per pool row ----------------
__global__ __launch_bounds__(256) void gather_kernel(
    const float* __restrict__ summaries,
    const float* __restrict__ pool,
    const int* __restrict__ src,
    float* __restrict__ outPool, int D) {
    int p = blockIdx.x;
    int s = src[p];
    const float* row = (s >= 0) ? (summaries + (size_t)s * D) : (pool + (size_t)p * D);
    float* o = outPool + (size_t)p * D;
    if ((D & 3) == 0) {
        for (int k = (threadIdx.x << 2); k < D; k += (blockDim.x << 2)) {
            float4 v = *(const float4*)(row + k);
            *(float4*)(o + k) = v;
        }
    } else {
        for (int k = threadIdx.x; k < D; k += blockDim.x) o[k] = row[k];
    }
}

extern "C" void kernel_launch(void* const* d_in, const int* in_sizes, int n_in,
                              void* d_out, int out_size, void* d_ws, size_t ws_size,
                              hipStream_t stream) {
    const float* summaries  = (const float*)d_in[0];
    const float* scores     = (const float*)d_in[1];
    const float* pool       = (const float*)d_in[2];
    const float* priorities = (const float*)d_in[3];
    const int*   count      = (const int*)d_in[4];

    int N = in_sizes[1];            // 16384
    int P = in_sizes[3];            // 4096
    int D = in_sizes[0] / N;        // 1024

    float* outPool  = (float*)d_out;
    float* outPrior = outPool + (size_t)P * D;
    float* outCnt   = outPrior + P;
    int*   srcWs    = (int*)d_ws;   // P ints; must survive into gather

    // scratch lives inside outPool: gather fully overwrites it at the end
    float* cval     = outPool;
    int*   csrc     = (int*)outPool + 1 * N;
    float* cvalS    = outPool + 3 * N;
    float* wval     = outPool + 4 * N;
    int*   wsrc     = (int*)outPool + 5 * N;
    int*   writeNum = (int*)outPool + 6 * N;
    float* evV      = outPool + 7 * N;                 // N + 64
    int*   evId     = (int*)outPool + 8 * N + 64;      // N + 64
    int*   survW    = (int*)outPool + 10 * N + 128;    // N
    int*   cnt2     = (int*)outPool + 11 * N + 192;    // N
    int*   cnt4     = (int*)outPool + 12 * N + 192;    // P + N
    int*   meta     = (int*)outPool + 11 * N + 128;    // 8

    const int nb2 = (N + 255) / 256;
    const int nb4 = (P + N + 255) / 256;
    const int ty  = (P + N + K2T - 1) / K2T;           // K2T == K4T == 512

    dim3 g2(nb2, ty), g4(nb4, ty);

    hipMemsetAsync(cnt2, 0, (size_t)N * sizeof(int), stream);
    hipMemsetAsync(cnt4, 0, (size_t)(P + N) * sizeof(int), stream);

    k1_scan<<<1, 1024, 0, stream>>>(scores, priorities, count, N, P,
                                    outPrior, outCnt, srcWs, cval, csrc, meta);
    k2_count<<<g2, 256, 0, stream>>>(outPrior, cval, meta, cnt2);
    k3_compact<<<1, 1024, 0, stream>>>(cval, csrc, cnt2, meta, cvalS, wval, wsrc, writeNum);
    k4_count<<<g4, 256, 0, stream>>>(outPrior, cvalS, meta, P, cnt4);
    k4_scatter<<<nb4, 256, 0, stream>>>(outPrior, cvalS, writeNum, meta, P, cnt4,
                                        evV, evId, survW);
    k5_chain<<<1, 1024, 0, stream>>>(evV, evId, meta, P, wval, wsrc, survW,
                                     outPrior, srcWs);
    gather_kernel<<<P, 256, 0, stream>>>(summaries, pool, srcWs, outPool, D);
}